// Round 1
// baseline (194.884 us; speedup 1.0000x reference)
//
#include <hip/hip_runtime.h>
#include <stdint.h>

typedef short bfrag __attribute__((ext_vector_type(8)));   // 8 bf16 = 4 VGPRs
typedef float f32x4 __attribute__((ext_vector_type(4)));

__device__ __forceinline__ ushort f2bf(float x){
  union { float f; uint32_t u; } c; c.f = x;
  uint32_t r = (c.u + 0x7fffu + ((c.u >> 16) & 1u)) >> 16;
  return (ushort)r;
}

__device__ __forceinline__ void load_lds16(const void* g, void* l){
  __builtin_amdgcn_global_load_lds((const __attribute__((address_space(1))) void*)g,
                                   (__attribute__((address_space(3))) void*)l,
                                   16, 0, 0);
}

__global__ void cast_f32_bf16(const float* __restrict__ in, ushort* __restrict__ out, int n4){
  int i = blockIdx.x * blockDim.x + threadIdx.x;
  if (i < n4){
    float4 f = ((const float4*)in)[i];
    ushort4 u;
    u.x = f2bf(f.x); u.y = f2bf(f.y); u.z = f2bf(f.z); u.w = f2bf(f.w);
    ((ushort4*)out)[i] = u;
  }
}

// C[m,n] = sum_k A[m,k]*B[n,k] + bias[n];  A:[M,K] bf16, B:[N,K] bf16, both row-major.
// EPI==1: scatter bf16 into q/k/v [B*NH][S][HD];  EPI==2: f32 into dout[M][N].
template<int EPI>
__global__ __launch_bounds__(256)
void gemm_bt(const ushort* __restrict__ A, const ushort* __restrict__ B,
             const float* __restrict__ bias,
             ushort* __restrict__ dq, ushort* __restrict__ dk, ushort* __restrict__ dv,
             float* __restrict__ dout,
             int M, int N, int K)
{
  __shared__ ushort Alds[2][128*32];
  __shared__ ushort Blds[2][128*32];
  const int t = threadIdx.x;
  const int w = t >> 6, l = t & 63;
  const int lr = l & 15, lg = l >> 4;
  const int m0 = blockIdx.x * 128, n0 = blockIdx.y * 128;
  const int wm = (w >> 1) * 64, wn = (w & 1) * 64;

  f32x4 acc[4][4] = {};

  auto stage = [&](int buf, int kt){
#pragma unroll
    for (int i = 0; i < 2; i++){
      const int row = i*64 + w*16 + (l >> 2);
      const int ce  = (l & 3) * 8;
      load_lds16(A + (size_t)(m0 + row) * K + kt*32 + ce, &Alds[buf][(i*64 + w*16) * 32]);
      load_lds16(B + (size_t)(n0 + row) * K + kt*32 + ce, &Blds[buf][(i*64 + w*16) * 32]);
    }
  };

  const int nk = K >> 5;
  int cur = 0;
  stage(0, 0);
  __syncthreads();
  for (int kt = 0; kt < nk; kt++){
    if (kt + 1 < nk) stage(cur ^ 1, kt + 1);
    bfrag af[4], bfv[4];
#pragma unroll
    for (int f = 0; f < 4; f++){
      af[f]  = *(const bfrag*)&Alds[cur][(wm + f*16 + lr) * 32 + lg * 8];
      bfv[f] = *(const bfrag*)&Blds[cur][(wn + f*16 + lr) * 32 + lg * 8];
    }
#pragma unroll
    for (int mf = 0; mf < 4; mf++)
#pragma unroll
      for (int nf = 0; nf < 4; nf++)
        acc[mf][nf] = __builtin_amdgcn_mfma_f32_16x16x32_bf16(af[mf], bfv[nf], acc[mf][nf], 0, 0, 0);
    __syncthreads();
    cur ^= 1;
  }

#pragma unroll
  for (int mf = 0; mf < 4; mf++){
#pragma unroll
    for (int nf = 0; nf < 4; nf++){
      const int col = n0 + wn + nf*16 + lr;
      const float bs = bias[col];
#pragma unroll
      for (int r = 0; r < 4; r++){
        const int row = m0 + wm + mf*16 + lg*4 + r;
        const float vv = acc[mf][nf][r] + bs;
        if (EPI == 1){
          const int which = col >> 10;
          const int hd = col & 1023;
          const int bb = row >> 11, s = row & 2047;
          ushort* dst = (which == 0) ? dq : (which == 1) ? dk : dv;
          dst[((size_t)((bb << 4) + (hd >> 6)) * 2048 + s) * 64 + (hd & 63)] = f2bf(vv);
        } else {
          dout[(size_t)row * N + col] = vv;
        }
      }
    }
  }
}

// Flash attention: one block = 128 q-rows of one (b,h); 4 waves x 32 rows.
// K tile [64][128B] staged by global_load_lds with pre-swizzled SOURCE (linear dest),
// read with byte ^ ((row&7)<<4).  V staged transposed [d][k] swizzled.  P via swizzled
// per-wave LDS round-trip.
__global__ __launch_bounds__(256)
void flash_attn(const ushort* __restrict__ q, const ushort* __restrict__ k,
                const ushort* __restrict__ v, const float* __restrict__ mask,
                ushort* __restrict__ ao)
{
  __shared__ ushort Klds[64*64];
  __shared__ ushort Vlds[64*64];
  __shared__ ushort Plds[4][32*64];
  const int t = threadIdx.x;
  const int w = t >> 6, l = t & 63;
  const int lr = l & 15, lg = l >> 4;
  const int bh = blockIdx.y;
  const int b = bh >> 4, h = bh & 15;
  const int q0 = blockIdx.x * 128;
  const ushort* qb = q + (size_t)bh * 2048 * 64;
  const ushort* kb = k + (size_t)bh * 2048 * 64;
  const ushort* vb = v + (size_t)bh * 2048 * 64;
  const float* mb = mask + b * 2048;

  bfrag qf[2][2];
#pragma unroll
  for (int mf = 0; mf < 2; mf++)
#pragma unroll
    for (int kf = 0; kf < 2; kf++){
      const int row = q0 + w*32 + mf*16 + lr;
      qf[mf][kf] = *(const bfrag*)(qb + (size_t)row * 64 + kf*32 + lg*8);
    }

  float mrun[2][4], lrun[2][4];
  f32x4 oacc[2][4] = {};
#pragma unroll
  for (int mf = 0; mf < 2; mf++)
#pragma unroll
    for (int r = 0; r < 4; r++){ mrun[mf][r] = -1e30f; lrun[mf][r] = 0.f; }

  for (int kv0 = 0; kv0 < 2048; kv0 += 64){
    __syncthreads();
    // stage K: linear LDS dest, inverse-swizzled global source
#pragma unroll
    for (int i = 0; i < 2; i++){
      const int dest = i*4096 + t*16;
      const int row = dest >> 7;
      const int pc  = dest & 127;
      const char* g = (const char*)(kb + (size_t)kv0 * 64) + row*128 + (pc ^ ((row & 7) << 4));
      load_lds16(g, (char*)Klds + i*4096 + w*1024);
    }
    // stage V transposed (Vt[d][k]) + swizzled
    {
      const ushort* gv = vb + (size_t)(kv0 + l) * 64 + w*16;
      bfrag v0 = *(const bfrag*)gv;
      bfrag v1 = *(const bfrag*)(gv + 8);
#pragma unroll
      for (int j = 0; j < 8; j++){
        int d = w*16 + j;
        *(ushort*)((char*)Vlds + d*128 + ((l*2) ^ ((d & 7) << 4))) = (ushort)v0[j];
        d = w*16 + 8 + j;
        *(ushort*)((char*)Vlds + d*128 + ((l*2) ^ ((d & 7) << 4))) = (ushort)v1[j];
      }
    }
    __syncthreads();

    // S = Q K^T
    bfrag bk[4][2];
#pragma unroll
    for (int nf = 0; nf < 4; nf++)
#pragma unroll
      for (int kf = 0; kf < 2; kf++){
        const int row = nf*16 + lr;
        const int kbyte = kf*64 + lg*16;
        bk[nf][kf] = *(const bfrag*)((const char*)Klds + row*128 + (kbyte ^ ((row & 7) << 4)));
      }
    f32x4 sa[2][4] = {};
#pragma unroll
    for (int mf = 0; mf < 2; mf++)
#pragma unroll
      for (int nf = 0; nf < 4; nf++)
#pragma unroll
        for (int kf = 0; kf < 2; kf++)
          sa[mf][nf] = __builtin_amdgcn_mfma_f32_16x16x32_bf16(qf[mf][kf], bk[nf][kf], sa[mf][nf], 0, 0, 0);

    float mk[4];
#pragma unroll
    for (int nf = 0; nf < 4; nf++) mk[nf] = mb[kv0 + nf*16 + lr];

#pragma unroll
    for (int mf = 0; mf < 2; mf++){
#pragma unroll
      for (int r = 0; r < 4; r++){
        float s0 = sa[mf][0][r]*0.125f + mk[0];
        float s1 = sa[mf][1][r]*0.125f + mk[1];
        float s2 = sa[mf][2][r]*0.125f + mk[2];
        float s3 = sa[mf][3][r]*0.125f + mk[3];
        float mx = fmaxf(fmaxf(s0, s1), fmaxf(s2, s3));
        mx = fmaxf(mx, __shfl_xor(mx, 1));
        mx = fmaxf(mx, __shfl_xor(mx, 2));
        mx = fmaxf(mx, __shfl_xor(mx, 4));
        mx = fmaxf(mx, __shfl_xor(mx, 8));
        const float mnew = fmaxf(mrun[mf][r], mx);
        const float c = __expf(mrun[mf][r] - mnew);
        mrun[mf][r] = mnew;
        const float p0 = __expf(s0 - mnew);
        const float p1 = __expf(s1 - mnew);
        const float p2 = __expf(s2 - mnew);
        const float p3 = __expf(s3 - mnew);
        float rs = p0 + p1 + p2 + p3;
        rs += __shfl_xor(rs, 1);
        rs += __shfl_xor(rs, 2);
        rs += __shfl_xor(rs, 4);
        rs += __shfl_xor(rs, 8);
        lrun[mf][r] = lrun[mf][r] * c + rs;
#pragma unroll
        for (int nf = 0; nf < 4; nf++) oacc[mf][nf][r] *= c;
        const int prow = mf*16 + lg*4 + r;
        const int sw = (prow & 7) << 4;
        char* pbase = (char*)&Plds[w][0] + prow*128;
        *(ushort*)(pbase + (((lr      )*2) ^ sw)) = f2bf(p0);
        *(ushort*)(pbase + (((16 + lr )*2) ^ sw)) = f2bf(p1);
        *(ushort*)(pbase + (((32 + lr )*2) ^ sw)) = f2bf(p2);
        *(ushort*)(pbase + (((48 + lr )*2) ^ sw)) = f2bf(p3);
      }
    }

    // O += P V
    bfrag bv[4][2], ap[2][2];
#pragma unroll
    for (int nf = 0; nf < 4; nf++)
#pragma unroll
      for (int kf = 0; kf < 2; kf++){
        const int d = nf*16 + lr;
        const int kbyte = kf*64 + lg*16;
        bv[nf][kf] = *(const bfrag*)((const char*)Vlds + d*128 + (kbyte ^ ((d & 7) << 4)));
      }
#pragma unroll
    for (int mf = 0; mf < 2; mf++)
#pragma unroll
      for (int kf = 0; kf < 2; kf++){
        const int row = mf*16 + lr;
        const int kbyte = kf*64 + lg*16;
        ap[mf][kf] = *(const bfrag*)((const char*)&Plds[w][0] + row*128 + (kbyte ^ ((row & 7) << 4)));
      }
#pragma unroll
    for (int mf = 0; mf < 2; mf++)
#pragma unroll
      for (int nf = 0; nf < 4; nf++)
#pragma unroll
        for (int kf = 0; kf < 2; kf++)
          oacc[mf][nf] = __builtin_amdgcn_mfma_f32_16x16x32_bf16(ap[mf][kf], bv[nf][kf], oacc[mf][nf], 0, 0, 0);
  }

#pragma unroll
  for (int mf = 0; mf < 2; mf++)
#pragma unroll
    for (int nf = 0; nf < 4; nf++)
#pragma unroll
      for (int r = 0; r < 4; r++){
        const int grow = b*2048 + q0 + w*32 + mf*16 + lg*4 + r;
        const int col = h*64 + nf*16 + lr;
        ao[(size_t)grow * 1024 + col] = f2bf(oacc[mf][nf][r] / lrun[mf][r]);
      }
}

extern "C" void kernel_launch(void* const* d_in, const int* in_sizes, int n_in,
                              void* d_out, int out_size, void* d_ws, size_t ws_size,
                              hipStream_t stream)
{
  (void)in_sizes; (void)n_in; (void)out_size; (void)ws_size;
  const float* hs   = (const float*)d_in[0];
  const float* mask = (const float*)d_in[1];
  const float* wqkv = (const float*)d_in[2];
  const float* bqkv = (const float*)d_in[3];
  const float* wout = (const float*)d_in[4];
  const float* bout = (const float*)d_in[5];
  float* out = (float*)d_out;

  char* ws = (char*)d_ws;
  ushort* hs_bf = (ushort*)(ws);                 // 4096*1024   bf16 (8 MB)
  ushort* w1_bf = (ushort*)(ws + 8388608);       // 3072*1024   bf16 (6 MB)
  ushort* w2_bf = (ushort*)(ws + 14680064);      // 1024*1024   bf16 (2 MB)
  ushort* q_bf  = (ushort*)(ws + 16777216);      // [32][2048][64] bf16 (8 MB)
  ushort* k_bf  = (ushort*)(ws + 25165824);
  ushort* v_bf  = (ushort*)(ws + 33554432);
  ushort* ao_bf = (ushort*)(ws + 41943040);      // [4096][1024] bf16 (8 MB)

  cast_f32_bf16<<<4096, 256, 0, stream>>>(hs,   hs_bf, 4194304/4);
  cast_f32_bf16<<<3072, 256, 0, stream>>>(wqkv, w1_bf, 3145728/4);
  cast_f32_bf16<<<1024, 256, 0, stream>>>(wout, w2_bf, 1048576/4);

  gemm_bt<1><<<dim3(32, 24), 256, 0, stream>>>(hs_bf, w1_bf, bqkv,
                                               q_bf, k_bf, v_bf, nullptr,
                                               4096, 3072, 1024);
  flash_attn<<<dim3(16, 32), 256, 0, stream>>>(q_bf, k_bf, v_bf, mask, ao_bf);
  gemm_bt<2><<<dim3(32, 8), 256, 0, stream>>>(ao_bf, w2_bf, bout,
                                              nullptr, nullptr, nullptr, out,
                                              4096, 1024, 1024);
}